// Round 8
// baseline (3473.577 us; speedup 1.0000x reference)
//
#include <hip/hip_runtime.h>

#define H      51
#define T_IN   512
#define T_TOT  576
#define PITCH  52
// float offsets within smem
#define OFF_W1 0                          // Whh1: 204 x 52
#define OFF_W3 (204 * PITCH)              // Wih3 gates f,g,o: 153 x 52
#define OFF_P  (OFF_W3 + 153 * PITCH)     // partial buf: [2 elem][4 wave][52] float4
#define OFF_HB (OFF_P + 2 * 4 * PITCH * 4)// head partials: [4 wave][2 elem]
#define LDSFL  (OFF_HB + 16)              // 20,244 floats = 80,976 B (2 blocks/CU)

__device__ __forceinline__ float bf2f(unsigned short u) {
    return __uint_as_float(((unsigned int)u) << 16);
}
__device__ __forceinline__ unsigned short f2bf(float f) {
    unsigned int u = __float_as_uint(f);
    u += 0x7fffu + ((u >> 16) & 1u);
    return (unsigned short)(u >> 16);
}
__device__ __forceinline__ float wget(const void* p, int i, bool is16) {
    return is16 ? bf2f(((const unsigned short*)p)[i]) : ((const float*)p)[i];
}
__device__ __forceinline__ float rl(float v, int k) {
    return __uint_as_float((unsigned int)__builtin_amdgcn_readlane((int)__float_as_uint(v), k));
}
__device__ __forceinline__ float sigm(float x) {
    x = fminf(fmaxf(x, -30.f), 30.f);
    return 1.f / (1.f + __expf(-x));
}
__device__ __forceinline__ float tanh_f(float x) {
    x = fminf(fmaxf(x, -15.f), 15.f);
    float e = __expf(2.f * x);
    return (e - 1.f) / (e + 1.f);
}
__device__ __forceinline__ float f4e(float4 v, int i) {
    return i == 0 ? v.x : i == 1 ? v.y : i == 2 ? v.z : v.w;
}

#define L13(M) M(0) M(1) M(2) M(3) M(4) M(5) M(6) M(7) M(8) M(9) M(10) M(11) M(12)

// Round-8: distributed UPD. 512 blocks x 4 waves, 2 elems/block (round-0
// geometry; round-7 proved 8-wave fusion prices barriers at 8-wave skew).
// Wave w owns k-slice kbR=13w of the register matrices and kbL of the LDS
// matrices. KEY CHANGE vs round-0: each wave computes the cell update ONLY
// for j in its slice-union [base, ...), packed (j,e) -> lane (j-base)*2+e.
// h then stays in ONE register per layer per wave, and the next phase's
// h[k] broadcast is readlane((k-base)*2+e) -- the h LDS write+barrier+read
// round-trip (3x ~140cy/step on the serial chain) is deleted. Partial
// exchange unchanged; biases (+x*Wih1 for L1) folded after the partial sum
// (all-wave acc=0 init); head = masked in-wave shuffle reduce + 8-float LDS
// exchange piggybacked on the existing 6th barrier. Barriers still 6/step.
// Register delta ~ -3 (h 6->3 regs; c 3 regs now used by all waves but was
// already allocated). Spill canary: WRITE_SIZE must stay ~3.8 MB.
extern "C" __global__ void __launch_bounds__(256)
__attribute__((amdgpu_waves_per_eu(2, 2)))
lstm3_kernel(const void* g_in,  const void* g_Wih1, const void* g_Whh1,
             const void* g_bih1, const void* g_bhh1,
             const void* g_Wih2, const void* g_Whh2, const void* g_bih2, const void* g_bhh2,
             const void* g_Wih3, const void* g_Whh3, const void* g_bih3, const void* g_bhh3,
             const void* g_Wlin, const void* g_blin, void* g_out)
{
    extern __shared__ float smem[];

    const int tid  = threadIdx.x;
    const int lane = tid & 63;
    const int wid  = tid >> 6;
    const int eb   = blockIdx.x * 2;
    const int jeff = (lane < H) ? lane : (H - 1);

    // ---- dtype sniff (proven on this harness)
    bool is16 = true;
    {
        const unsigned short* p = (const unsigned short*)g_Wih1;
        for (int i = 0; i < 204; ++i) {
            float v = fabsf(bf2f(p[i]));
            if (!(v < 0.2f)) is16 = false;
        }
    }

    // ---- LDS staging (round-0 layout)
    for (int i = tid; i < 204 * PITCH; i += 256) {
        int r = i / PITCH, k = i - r * PITCH;
        smem[OFF_W1 + i] = (k < H) ? wget(g_Whh1, r * H + k, is16) : 0.f;
    }
    for (int i = tid; i < 153 * PITCH; i += 256) {
        int r = i / PITCH, k = i - r * PITCH;
        smem[OFF_W3 + i] = (k < H) ? wget(g_Wih3, (H + r) * H + k, is16) : 0.f;
    }
    __syncthreads();

    const int kbR  = 13 * wid;                                  // register k-slice
    const int kbL  = (wid == 0) ? 0 : (wid == 1) ? 12 : (wid == 2) ? 28 : 40;
    const int nbL  = (wid == 1) ? 4 : 3;                        // float4 blocks in LDS slice
    const int base = (wid == 0) ? 0 : (wid == 1) ? 12 : (wid == 2) ? 26 : 39; // union base
    const int dR   = (kbR - base) * 2;                          // rl idx offset, reg slices
    const int dL   = (kbL - base) * 2;                          // rl idx offset, LDS slices
    const int jj   = base + (lane >> 1);                        // my UPD row
    const int jcc  = (jj < H) ? jj : (H - 1);                   // clamped (dup, harmless)
    const bool canon = (jj >= kbR) && (jj < kbR + 13) && (jj < H); // head ownership

#define WC(srcp, row, kk) (((kbR + (kk)) < H) ? wget(srcp, (row) * H + kbR + (kk), is16) : 0.f)
#define DECL13(p) float p##_0,p##_1,p##_2,p##_3,p##_4,p##_5,p##_6,p##_7,p##_8,p##_9,p##_10,p##_11,p##_12;
#define LOAD13(p, srcp, row) \
    p##_0 = WC(srcp, row, 0);  p##_1 = WC(srcp, row, 1);  p##_2 = WC(srcp, row, 2); \
    p##_3 = WC(srcp, row, 3);  p##_4 = WC(srcp, row, 4);  p##_5 = WC(srcp, row, 5); \
    p##_6 = WC(srcp, row, 6);  p##_7 = WC(srcp, row, 7);  p##_8 = WC(srcp, row, 8); \
    p##_9 = WC(srcp, row, 9);  p##_10 = WC(srcp, row, 10); p##_11 = WC(srcp, row, 11); \
    p##_12 = WC(srcp, row, 12);

    DECL13(wih2g0) DECL13(wih2g1) DECL13(wih2g2) DECL13(wih2g3)
    DECL13(whh2g0) DECL13(whh2g1) DECL13(whh2g2) DECL13(whh2g3)
    DECL13(whh3g0) DECL13(whh3g1) DECL13(whh3g2) DECL13(whh3g3)
    DECL13(wih3i)
    LOAD13(wih2g0, g_Wih2, 0 * H + jeff) LOAD13(wih2g1, g_Wih2, 1 * H + jeff)
    LOAD13(wih2g2, g_Wih2, 2 * H + jeff) LOAD13(wih2g3, g_Wih2, 3 * H + jeff)
    LOAD13(whh2g0, g_Whh2, 0 * H + jeff) LOAD13(whh2g1, g_Whh2, 1 * H + jeff)
    LOAD13(whh2g2, g_Whh2, 2 * H + jeff) LOAD13(whh2g3, g_Whh2, 3 * H + jeff)
    LOAD13(whh3g0, g_Whh3, 0 * H + jeff) LOAD13(whh3g1, g_Whh3, 1 * H + jeff)
    LOAD13(whh3g2, g_Whh3, 2 * H + jeff) LOAD13(whh3g3, g_Whh3, 3 * H + jeff)
    LOAD13(wih3i,  g_Wih3, 0 * H + jeff)

    // ---- UPD-lane constants (row jcc, (j,e)-packed lanes)
    const float bU1_0 = wget(g_bih1, 0*H+jcc, is16) + wget(g_bhh1, 0*H+jcc, is16);
    const float bU1_1 = wget(g_bih1, 1*H+jcc, is16) + wget(g_bhh1, 1*H+jcc, is16);
    const float bU1_2 = wget(g_bih1, 2*H+jcc, is16) + wget(g_bhh1, 2*H+jcc, is16);
    const float bU1_3 = wget(g_bih1, 3*H+jcc, is16) + wget(g_bhh1, 3*H+jcc, is16);
    const float bU2_0 = wget(g_bih2, 0*H+jcc, is16) + wget(g_bhh2, 0*H+jcc, is16);
    const float bU2_1 = wget(g_bih2, 1*H+jcc, is16) + wget(g_bhh2, 1*H+jcc, is16);
    const float bU2_2 = wget(g_bih2, 2*H+jcc, is16) + wget(g_bhh2, 2*H+jcc, is16);
    const float bU2_3 = wget(g_bih2, 3*H+jcc, is16) + wget(g_bhh2, 3*H+jcc, is16);
    const float bU3_0 = wget(g_bih3, 0*H+jcc, is16) + wget(g_bhh3, 0*H+jcc, is16);
    const float bU3_1 = wget(g_bih3, 1*H+jcc, is16) + wget(g_bhh3, 1*H+jcc, is16);
    const float bU3_2 = wget(g_bih3, 2*H+jcc, is16) + wget(g_bhh3, 2*H+jcc, is16);
    const float bU3_3 = wget(g_bih3, 3*H+jcc, is16) + wget(g_bhh3, 3*H+jcc, is16);
    const float wiU_0 = wget(g_Wih1, 0*H+jcc, is16);
    const float wiU_1 = wget(g_Wih1, 1*H+jcc, is16);
    const float wiU_2 = wget(g_Wih1, 2*H+jcc, is16);
    const float wiU_3 = wget(g_Wih1, 3*H+jcc, is16);
    const float wlinH = canon ? wget(g_Wlin, jcc, is16) : 0.f;  // masked head weight
    const float blinr = wget(g_blin, 0, is16);

    const float4* A1g0 = (const float4*)(smem + OFF_W1 + (0*H + jeff) * PITCH + kbL);
    const float4* A1g1 = (const float4*)(smem + OFF_W1 + (1*H + jeff) * PITCH + kbL);
    const float4* A1g2 = (const float4*)(smem + OFF_W1 + (2*H + jeff) * PITCH + kbL);
    const float4* A1g3 = (const float4*)(smem + OFF_W1 + (3*H + jeff) * PITCH + kbL);
    const float4* A3f  = (const float4*)(smem + OFF_W3 + (      jeff) * PITCH + kbL);
    const float4* A3g  = (const float4*)(smem + OFF_W3 + (H   + jeff) * PITCH + kbL);
    const float4* A3o  = (const float4*)(smem + OFF_W3 + (2*H + jeff) * PITCH + kbL);
    float4* ebufP = (float4*)(smem + OFF_P);
    const float4* pbE = ebufP + (lane & 1) * 4 * PITCH;         // my-elem region
    float* hbx = smem + OFF_HB;

    float h1=0.f, h2=0.f, h3=0.f;          // (j,e)-packed, one reg per layer
    float c1=0.f, c2=0.f, c3=0.f;          // per-lane cell state, all waves
    float xf0=0.f, xf1=0.f;                // future-phase x (all waves)

    const unsigned short* in16 = (const unsigned short*)g_in;
    const float*          in32 = (const float*)g_in;
    unsigned short* o16 = (unsigned short*)g_out;
    float*          o32 = (float*)g_out;

#define P2(kk) { \
    float s0_ = rl(h1, dR+2*(kk)), s1_ = rl(h1, dR+2*(kk)+1); \
    float r0_ = rl(h2, dR+2*(kk)), r1_ = rl(h2, dR+2*(kk)+1); \
    a0_0=fmaf(wih2g0_##kk,s0_,a0_0); a0_1=fmaf(wih2g0_##kk,s1_,a0_1); \
    a1_0=fmaf(wih2g1_##kk,s0_,a1_0); a1_1=fmaf(wih2g1_##kk,s1_,a1_1); \
    a2_0=fmaf(wih2g2_##kk,s0_,a2_0); a2_1=fmaf(wih2g2_##kk,s1_,a2_1); \
    a3_0=fmaf(wih2g3_##kk,s0_,a3_0); a3_1=fmaf(wih2g3_##kk,s1_,a3_1); \
    a0_0=fmaf(whh2g0_##kk,r0_,a0_0); a0_1=fmaf(whh2g0_##kk,r1_,a0_1); \
    a1_0=fmaf(whh2g1_##kk,r0_,a1_0); a1_1=fmaf(whh2g1_##kk,r1_,a1_1); \
    a2_0=fmaf(whh2g2_##kk,r0_,a2_0); a2_1=fmaf(whh2g2_##kk,r1_,a2_1); \
    a3_0=fmaf(whh2g3_##kk,r0_,a3_0); a3_1=fmaf(whh2g3_##kk,r1_,a3_1); }

#define P3(kk) { \
    float s0_ = rl(h2, dR+2*(kk)), s1_ = rl(h2, dR+2*(kk)+1); \
    float r0_ = rl(h3, dR+2*(kk)), r1_ = rl(h3, dR+2*(kk)+1); \
    a0_0=fmaf(wih3i_##kk,s0_,a0_0);  a0_1=fmaf(wih3i_##kk,s1_,a0_1); \
    a0_0=fmaf(whh3g0_##kk,r0_,a0_0); a0_1=fmaf(whh3g0_##kk,r1_,a0_1); \
    a1_0=fmaf(whh3g1_##kk,r0_,a1_0); a1_1=fmaf(whh3g1_##kk,r1_,a1_1); \
    a2_0=fmaf(whh3g2_##kk,r0_,a2_0); a2_1=fmaf(whh3g2_##kk,r1_,a2_1); \
    a3_0=fmaf(whh3g3_##kk,r0_,a3_0); a3_1=fmaf(whh3g3_##kk,r1_,a3_1); }

    // write my partial rows for both elems; RAW barrier
#define WRP() { \
    if (lane < H) { \
        ebufP[(0*4 + wid)*PITCH + lane] = make_float4(a0_0, a1_0, a2_0, a3_0); \
        ebufP[(1*4 + wid)*PITCH + lane] = make_float4(a0_1, a1_1, a2_1, a3_1); \
    } \
    __syncthreads(); }

    // distributed UPD: this lane's (j,e) gate-quad = sum of 4 waves' partials
    // + per-gate extra (bias / bias+x term). NO trailing barrier (call site).
#define UPDL(cm, hv, E0, E1, E2, E3) { \
    float4 q_ = pbE[0*PITCH + jcc]; \
    float4 t_ = pbE[1*PITCH + jcc]; q_.x+=t_.x; q_.y+=t_.y; q_.z+=t_.z; q_.w+=t_.w; \
    t_ = pbE[2*PITCH + jcc]; q_.x+=t_.x; q_.y+=t_.y; q_.z+=t_.z; q_.w+=t_.w; \
    t_ = pbE[3*PITCH + jcc]; q_.x+=t_.x; q_.y+=t_.y; q_.z+=t_.z; q_.w+=t_.w; \
    float gi_ = q_.x + (E0), gf_ = q_.y + (E1), gg_ = q_.z + (E2), go_ = q_.w + (E3); \
    float i_ = sigm(gi_), f_ = sigm(gf_), g_ = tanh_f(gg_), o_ = sigm(go_); \
    cm = f_ * cm + i_ * g_; \
    hv = o_ * tanh_f(cm); }

#pragma clang loop unroll(disable)
    for (int t = 0; t < T_TOT; ++t) {
        float a0_0,a1_0,a2_0,a3_0,a0_1,a1_1,a2_1,a3_1;

        // x for this step: issued at loop top, consumed only after b1 (off-chain)
        float x0, x1;
        if (t < T_IN) {
            if (is16) {
                x0 = bf2f(in16[(size_t)(eb+0)*T_IN + t]);
                x1 = bf2f(in16[(size_t)(eb+1)*T_IN + t]);
            } else {
                x0 = in32[(size_t)(eb+0)*T_IN + t];
                x1 = in32[(size_t)(eb+1)*T_IN + t];
            }
        } else { x0 = xf0; x1 = xf1; }
        const float xsel = (lane & 1) ? x1 : x0;

        // ---------------- layer 1: Whh1@h1_old (LDS slice) ----------------
        a0_0=a1_0=a2_0=a3_0=a0_1=a1_1=a2_1=a3_1=0.f;
        for (int b = 0; b < nbL; ++b) {
            float4 u0 = A1g0[b], u1 = A1g1[b], u2 = A1g2[b], u3 = A1g3[b];
#pragma unroll
            for (int i = 0; i < 4; ++i) {
                int ix = dL + 8*b + 2*i;
                float s0 = rl(h1, ix), s1 = rl(h1, ix+1);
                a0_0 = fmaf(f4e(u0,i), s0, a0_0); a0_1 = fmaf(f4e(u0,i), s1, a0_1);
                a1_0 = fmaf(f4e(u1,i), s0, a1_0); a1_1 = fmaf(f4e(u1,i), s1, a1_1);
                a2_0 = fmaf(f4e(u2,i), s0, a2_0); a2_1 = fmaf(f4e(u2,i), s1, a2_1);
                a3_0 = fmaf(f4e(u3,i), s0, a3_0); a3_1 = fmaf(f4e(u3,i), s1, a3_1);
            }
        }
        WRP()                                              // b1 (RAW)
        UPDL(c1, h1, fmaf(wiU_0, xsel, bU1_0), fmaf(wiU_1, xsel, bU1_1),
                     fmaf(wiU_2, xsel, bU1_2), fmaf(wiU_3, xsel, bU1_3))
        __syncthreads();                                   // b2 (WAR)

        // ---------------- layer 2: all-register ----------------
        a0_0=a1_0=a2_0=a3_0=a0_1=a1_1=a2_1=a3_1=0.f;
        L13(P2)
        WRP()                                              // b3
        UPDL(c2, h2, bU2_0, bU2_1, bU2_2, bU2_3)
        __syncthreads();                                   // b4

        // ---------------- layer 3: LDS f/g/o + regs i,Whh3 ----------------
        a0_0=a1_0=a2_0=a3_0=a0_1=a1_1=a2_1=a3_1=0.f;
        for (int b = 0; b < nbL; ++b) {
            float4 uf = A3f[b], ug = A3g[b], uo = A3o[b];
#pragma unroll
            for (int i = 0; i < 4; ++i) {
                int ix = dL + 8*b + 2*i;
                float s0 = rl(h2, ix), s1 = rl(h2, ix+1);
                a1_0 = fmaf(f4e(uf,i), s0, a1_0); a1_1 = fmaf(f4e(uf,i), s1, a1_1);
                a2_0 = fmaf(f4e(ug,i), s0, a2_0); a2_1 = fmaf(f4e(ug,i), s1, a2_1);
                a3_0 = fmaf(f4e(uo,i), s0, a3_0); a3_1 = fmaf(f4e(uo,i), s1, a3_1);
            }
        }
        L13(P3)
        WRP()                                              // b5
        UPDL(c3, h3, bU3_0, bU3_1, bU3_2, bU3_3)

        // ---------------- head: masked in-wave reduce, piggyback b6 -------
        float hp = wlinH * h3;                 // wlinH=0 on non-canonical lanes
        hp += __shfl_xor(hp, 2, 64);  hp += __shfl_xor(hp, 4, 64);
        hp += __shfl_xor(hp, 8, 64);  hp += __shfl_xor(hp, 16, 64);
        hp += __shfl_xor(hp, 32, 64);          // parity (elem) preserved
        if (lane < 2) hbx[wid * 2 + lane] = hp;
        __syncthreads();                                   // b6 (WAR + head RAW)
        float ox0 = hbx[0] + hbx[2] + hbx[4] + hbx[6] + blinr;
        float ox1 = hbx[1] + hbx[3] + hbx[5] + hbx[7] + blinr;
        xf0 = ox0; xf1 = ox1;
        if (wid == 0 && lane < 2) {
            float ov = (lane == 1) ? ox1 : ox0;
            if (is16) o16[(size_t)(eb + lane) * T_TOT + t] = f2bf(ov);
            else      o32[(size_t)(eb + lane) * T_TOT + t] = ov;
        }
    }
}

extern "C" void kernel_launch(void* const* d_in, const int* in_sizes, int n_in,
                              void* d_out, int out_size, void* d_ws, size_t ws_size,
                              hipStream_t stream) {
    (void)in_sizes; (void)n_in; (void)d_ws; (void)ws_size; (void)out_size;
    size_t shmem = LDSFL * sizeof(float);   // 80,976 B -> 2 blocks/CU
    hipFuncSetAttribute((const void*)lstm3_kernel,
                        hipFuncAttributeMaxDynamicSharedMemorySize, (int)shmem);
    lstm3_kernel<<<dim3(512), dim3(256), shmem, stream>>>(
        d_in[0],  d_in[1],  d_in[2],  d_in[3],  d_in[4],
        d_in[5],  d_in[6],  d_in[7],  d_in[8],
        d_in[9],  d_in[10], d_in[11], d_in[12],
        d_in[13], d_in[14], d_out);
}